// Round 4
// baseline (149.761 us; speedup 1.0000x reference)
//
#include <hip/hip_runtime.h>
#include <hip/hip_bf16.h>
#include <stdint.h>

// B=8, S=2048, D=256. out[b,d] = (1/S) sum_q (sum_k P_qk v_kd) / l_q,
// P_qk = exp(s_qk) (0 for masked k), l_q = sum_k P_qk.   [flash form]
//
// R14 = 133.6us (4-kernel). This round: flash-fuse pass1+wo into k_attn.
// pbuf (fp8 P round trip), lsum, and k_wo are DELETED. k_attn keeps O and l
// in registers per 16-q wave, staging K+V chunks (64KB dbuf) with counted
// vmcnt(16) + raw barriers; P goes through 8KB swizzled LDS so PV's MFMA
// B-fragment is one ds_read_b128. V gets a transposed+swizzled global layout
// vbt[b][chunk][d][k] written by proj (pads zeroed in k_cc: 0*garbage!=NaN).
//
// k_cc:     fp32->bf16 convert + key compaction (slot_of) + kbt/vbt pad-zero
//           + out zeroing.
// k_proj2b: QKV projection GEMM; z=0 -> qb (q pre-scaled 1/16), z=1 -> kbt
//           fragment tiles, z=2 -> vbt transposed-swizzled tiles.
// k_attn:   per (qblk64, b): loop k-chunks: QK^T (MFMA) -> exp -> P_lds ->
//           PV (MFMA, waves split by d) -> acc O,l in regs -> divide, mean-q,
//           atomicAdd out.

typedef short short8 __attribute__((ext_vector_type(8)));
typedef float floatx4 __attribute__((ext_vector_type(4)));

#define MFMA16(a, b, c) __builtin_amdgcn_mfma_f32_16x16x32_bf16((a), (b), (c), 0, 0, 0)

// async 16B/lane global->LDS DMA; LDS dst = wave-uniform base + lane*16
#define ASYNC16(gsrc, ldst)                                                    \
    __builtin_amdgcn_global_load_lds(                                          \
        (__attribute__((address_space(1))) void*)(void*)(gsrc),                \
        (__attribute__((address_space(3))) void*)(ldst), 16, 0, 0)

static __device__ __forceinline__ unsigned short f2bf(float f) {
    union { float f; unsigned u; } v; v.f = f;
    unsigned r = v.u + 0x7fffu + ((v.u >> 16) & 1u);
    return (unsigned short)(r >> 16);
}

// ------- k_cc: [0,2144) convert; [2144,2152) compact+pad-zero; rest zero ----
__global__ __launch_bounds__(256) void k_cc(
    const float* __restrict__ nodes, const float* __restrict__ Wq,
    const float* __restrict__ Wk, const float* __restrict__ Wv,
    unsigned short* __restrict__ nbf, unsigned short* __restrict__ wbf,
    const int* __restrict__ mask, int* __restrict__ cnt,
    int* __restrict__ slot_of /* [16384] */,
    unsigned short* __restrict__ kbt, unsigned short* __restrict__ vbt,
    float* __restrict__ outp /* 2048 f */)
{
    int blk = blockIdx.x;
    if (blk < 2144) {                              // fp32 -> bf16 convert
        int unit = blk * 256 + threadIdx.x;        // one unit = 8 elements
        const float* src;
        unsigned short* dst;
        int off;
        if (unit < 524288) {
            src = nodes; dst = nbf; off = unit * 8;
        } else {
            int j = (unit - 524288) * 8;
            int m = j >> 16;
            int r = j & 65535;
            src = (m == 0) ? Wq : (m == 1 ? Wk : Wv);
            dst = wbf + m * 65536;
            off = r;
        }
        float4 a = *(const float4*)(src + off);
        float4 b = *(const float4*)(src + off + 4);
        short8 o;
        o[0] = f2bf(a.x); o[1] = f2bf(a.y); o[2] = f2bf(a.z); o[3] = f2bf(a.w);
        o[4] = f2bf(b.x); o[5] = f2bf(b.y); o[6] = f2bf(b.z); o[7] = f2bf(b.w);
        *(short8*)(dst + off) = o;
        return;
    }
    if (blk < 2152) {                              // key compaction + inverse map
        if (threadIdx.x < 64) {
            int b = blk - 2144, lane = threadIdx.x;
            int base = 0;
            for (int c = 0; c < 2048; c += 64) {
                int m = mask[b * 2048 + c + lane];
                unsigned long long bal = __ballot(m != 0);
                int pre = __popcll(bal & ((1ull << lane) - 1ull));
                slot_of[b * 2048 + c + lane] = m ? (base + pre) : -1;
                base += __popcll(bal);
            }
            if (lane == 0) cnt[b] = base;
            int cntPad = (base + 63) & ~63;
            int pad = cntPad - base;               // [0, 64)
            // zero kbt pad slots (bf16 0.0; exp killed by bias anyway)
            short8 z8 = {};
            for (int i = lane; i < pad * 32; i += 64) {
                int slot = base + (i >> 5);
                int du = i & 31;
                size_t off = ((size_t)b * 32 + (slot >> 6)) * 16384
                           + ((size_t)du * 64 + (slot & 63)) * 8;
                *(short8*)(kbt + off) = z8;
            }
            // zero vbt pad slots: P=0 * garbage(NaN) would poison PV MFMA
            for (int i = lane; i < pad * 256; i += 64) {
                int s = base + (i >> 8);
                int d = i & 255;
                int byte = ((d * 64 + (s & 63)) * 2) ^ ((d & 7) << 4);
                vbt[((size_t)b * 32 + (s >> 6)) * 16384 + (byte >> 1)] = 0;
            }
        }
        return;
    }
    int idx = (blk - 2152) * 256 + threadIdx.x;    // [0, 512): out zero
    float4 z = {0.f, 0.f, 0.f, 0.f};
    if (idx < 512) ((float4*)outp)[idx] = z;
}

// ------- k_proj2b: 128x128 LDS-tiled GEMM, async staging --------------------
// grid (128, 2, 3); block 256 = 4 waves (2x2), wave computes 64x64.
__global__ __launch_bounds__(256) void k_proj2b(
    const unsigned short* __restrict__ nbf,
    const unsigned short* __restrict__ wbf,
    const float* __restrict__ bq, const float* __restrict__ bk,
    const float* __restrict__ bv,
    const int* __restrict__ slot_of,
    unsigned short* __restrict__ qb, unsigned short* __restrict__ kbt,
    unsigned short* __restrict__ vbt)
{
    __shared__ __align__(16) unsigned short As[128 * 64];
    __shared__ __align__(16) unsigned short Bs[128 * 64];
    int tid = threadIdx.x, lane = tid & 63, wave = tid >> 6;
    int wm = wave & 1, wn = wave >> 1;
    int l15 = lane & 15, quad = lane >> 4;
    int mBase = blockIdx.x * 128;
    int nBase = blockIdx.y * 128;
    int z = blockIdx.z;
    const unsigned short* W = wbf + z * 65536;

    floatx4 acc[4][4] = {};

    for (int kc = 0; kc < 256; kc += 64) {
#pragma unroll
        for (int i = 0; i < 4; ++i) {
            int p = i * 256 + wave * 64 + lane;
            int row = p >> 3;
            int col8 = (p & 7) ^ (row & 7);
            int goff = row * 256 + kc + col8 * 8;
            unsigned short* dstA = &As[(i * 256 + wave * 64) * 8];
            unsigned short* dstB = &Bs[(i * 256 + wave * 64) * 8];
            ASYNC16(nbf + mBase * 256 + goff, dstA);
            ASYNC16(W + nBase * 256 + goff, dstB);
        }
        __syncthreads();
#pragma unroll
        for (int ks = 0; ks < 2; ++ks) {
            int c8 = ks * 4 + quad;
            short8 af[4], bfr[4];
#pragma unroll
            for (int i = 0; i < 4; ++i) {
                int row = wm * 64 + i * 16 + l15;
                af[i] = *(const short8*)(&As[(row * 8 + (c8 ^ (row & 7))) * 8]);
            }
#pragma unroll
            for (int i = 0; i < 4; ++i) {
                int row = wn * 64 + i * 16 + l15;
                bfr[i] = *(const short8*)(&Bs[(row * 8 + (c8 ^ (row & 7))) * 8]);
            }
#pragma unroll
            for (int mi = 0; mi < 4; ++mi)
#pragma unroll
                for (int ni = 0; ni < 4; ++ni)
                    acc[mi][ni] = MFMA16(af[mi], bfr[ni], acc[mi][ni]);
        }
        __syncthreads();
    }

    const float* bias = (z == 0) ? bq : (z == 1 ? bk : bv);
    if (z == 1) {
        // K path: scatter into compacted fragment-tile layout, skip masked rows
#pragma unroll
        for (int mi = 0; mi < 4; ++mi)
#pragma unroll
            for (int ni = 0; ni < 4; ++ni) {
                int col = nBase + wn * 64 + ni * 16 + l15;
                float bval = bias[col];
                int du = col >> 3, cj = col & 7;
#pragma unroll
                for (int r = 0; r < 4; ++r) {
                    int row = mBase + wm * 64 + mi * 16 + quad * 4 + r;
                    int slot = slot_of[row];
                    if (slot >= 0) {
                        int b = row >> 11;
                        size_t off = ((size_t)b * 32 + (slot >> 6)) * 16384
                                   + ((size_t)du * 64 + (slot & 63)) * 8 + cj;
                        kbt[off] = f2bf(acc[mi][ni][r] + bval);
                    }
                }
            }
    } else if (z == 2) {
        // V path: transposed+swizzled [b][chunk][d(256)][k(64)] tiles
#pragma unroll
        for (int mi = 0; mi < 4; ++mi)
#pragma unroll
            for (int ni = 0; ni < 4; ++ni) {
                int col = nBase + wn * 64 + ni * 16 + l15;   // d
                float bval = bias[col];
#pragma unroll
                for (int r = 0; r < 4; ++r) {
                    int row = mBase + wm * 64 + mi * 16 + quad * 4 + r;
                    int slot = slot_of[row];
                    if (slot >= 0) {
                        int b = row >> 11;
                        int byte = ((col * 64 + (slot & 63)) * 2) ^ ((col & 7) << 4);
                        vbt[((size_t)b * 32 + (slot >> 6)) * 16384 + (byte >> 1)] =
                            f2bf(acc[mi][ni][r] + bval);
                    }
                }
            }
    } else {
        float scale = 0.0625f;                 // fold 1/sqrt(256) into q
#pragma unroll
        for (int mi = 0; mi < 4; ++mi)
#pragma unroll
            for (int ni = 0; ni < 4; ++ni) {
                int col = nBase + wn * 64 + ni * 16 + l15;
                float bval = bias[col];
#pragma unroll
                for (int r = 0; r < 4; ++r) {
                    int row = mBase + wm * 64 + mi * 16 + quad * 4 + r;
                    qb[row * 256 + col] = f2bf((acc[mi][ni][r] + bval) * scale);
                }
            }
    }
}

// ---------------- k_attn: fused QK^T -> exp -> PV -> out --------------------
// grid (32 qblk, 8 b); block 256 = 4 waves; wave owns 16 q for QK^T and
// d-tiles [wave*64, wave*64+64) for PV. O (unnormalized) and l stay in regs.
__global__ __launch_bounds__(256, 1) void k_attn(
    const unsigned short* __restrict__ qb, const unsigned short* __restrict__ kbt,
    const unsigned short* __restrict__ vbt, const int* __restrict__ cnt_g,
    float* __restrict__ outp)
{
    __shared__ __align__(16) unsigned short kt[2][16384];  // K dbuf 64 KB
    __shared__ __align__(16) unsigned short vt[2][16384];  // V dbuf 64 KB
    __shared__ __align__(16) unsigned short pls[4][1024];  // P per wave, 8 KB
    __shared__ float l_s[4][16];
    int tid = threadIdx.x, lane = tid & 63, wave = tid >> 6;
    int l15 = lane & 15, quad = lane >> 4;
    int b = blockIdx.y;
    int cnt = cnt_g[b];
    int nchunk = (cnt + 63) >> 6;
    int qBase = blockIdx.x * 64 + wave * 16;

    short8 qf[8];
#pragma unroll
    for (int ks = 0; ks < 8; ++ks)
        qf[ks] = *(const short8*)(qb + (b * 2048 + qBase + l15) * 256 + ks * 32 + quad * 8);

    // prologue: stage chunk 0 (K + V) into buf 0
    {
        const unsigned short* ksrc = kbt + ((size_t)b * 32) * 16384;
        const unsigned short* vsrc = vbt + ((size_t)b * 32) * 16384;
#pragma unroll
        for (int i = 0; i < 8; ++i) {
            int seg = wave * 8 + i;            // [0,32): 1KB segments
            ASYNC16(ksrc + seg * 512 + lane * 8, &kt[0][seg * 512]);
            ASYNC16(vsrc + seg * 512 + lane * 8, &vt[0][seg * 512]);
        }
    }

    float ls[4] = {};
    floatx4 acco[4][4] = {};                   // [q-tile][d-tile-local]
    int p = 0;
    for (int c = 0; c < nchunk; ++c, p ^= 1) {
        if (c + 1 < nchunk) {                  // prefetch next chunk
            const unsigned short* ksrc = kbt + ((size_t)b * 32 + c + 1) * 16384;
            const unsigned short* vsrc = vbt + ((size_t)b * 32 + c + 1) * 16384;
#pragma unroll
            for (int i = 0; i < 8; ++i) {
                int seg = wave * 8 + i;
                ASYNC16(ksrc + seg * 512 + lane * 8, &kt[p ^ 1][seg * 512]);
                ASYNC16(vsrc + seg * 512 + lane * 8, &vt[p ^ 1][seg * 512]);
            }
            asm volatile("s_waitcnt vmcnt(16)" ::: "memory");
        } else {
            asm volatile("s_waitcnt vmcnt(0)" ::: "memory");
        }
        __builtin_amdgcn_s_barrier();          // chunk c staged for all waves

        // ---- QK^T for this wave's 16 q over the chunk's 64 keys ----
        floatx4 sacc[4] = {};
#pragma unroll
        for (int ks = 0; ks < 8; ++ks)
#pragma unroll
            for (int nt = 0; nt < 4; ++nt) {
                short8 kf = *(const short8*)(&kt[p][((ks * 4 + quad) * 64 + nt * 16 + l15) * 8]);
                sacc[nt] = MFMA16(qf[ks], kf, sacc[nt]);
            }
#pragma unroll
        for (int nt = 0; nt < 4; ++nt) {
            float biasv = (c * 64 + nt * 16 + l15 < cnt) ? 0.0f : -1e30f;
#pragma unroll
            for (int r = 0; r < 4; ++r) {
                float e = __expf(sacc[nt][r] + biasv);
                ls[r] += e;
                int ql = quad * 4 + r;
                int byte = ((ql * 64 + nt * 16 + l15) * 2) ^ ((ql & 7) << 4);
                pls[wave][byte >> 1] = f2bf(e);
            }
        }
        asm volatile("s_waitcnt lgkmcnt(0)" ::: "memory");
        __builtin_amdgcn_sched_barrier(0);
        __builtin_amdgcn_s_barrier();          // P published to all waves

        // ---- PV: O^T[d][q] += V^T . P^T, wave owns 4 d-tiles, all 64 q ----
#pragma unroll
        for (int kr = 0; kr < 2; ++kr) {
            int pbyte = ((l15 * 64 + kr * 32 + quad * 8) * 2) ^ ((l15 & 7) << 4);
#pragma unroll
            for (int qt = 0; qt < 4; ++qt) {
                short8 pf = *(const short8*)(&pls[qt][pbyte >> 1]);
#pragma unroll
                for (int dtl = 0; dtl < 4; ++dtl) {
                    int dg = wave * 4 + dtl;
                    int vbyte = (((dg * 16 + l15) * 64 + kr * 32 + quad * 8) * 2)
                              ^ ((l15 & 7) << 4);
                    short8 vf = *(const short8*)((const char*)vt[p] + vbyte);
                    acco[qt][dtl] = MFMA16(vf, pf, acco[qt][dtl]);
                }
            }
        }
        __builtin_amdgcn_s_barrier();          // buf p consumed; safe to restage
    }

    // ---- l: butterfly over the 16 key-lanes; publish per-wave l ----
#pragma unroll
    for (int r = 0; r < 4; ++r) {
        float v = ls[r];
        v += __shfl_xor(v, 1); v += __shfl_xor(v, 2);
        v += __shfl_xor(v, 4); v += __shfl_xor(v, 8);
        ls[r] = v;
    }
    if (l15 == 0)
#pragma unroll
        for (int r = 0; r < 4; ++r) l_s[wave][quad * 4 + r] = ls[r];
    __syncthreads();

    float linv[4];
#pragma unroll
    for (int qt = 0; qt < 4; ++qt) linv[qt] = 1.0f / l_s[qt][l15];

    // ---- out[b,d] += (1/S) * sum_q O[q][d] / l_q ----
#pragma unroll
    for (int dtl = 0; dtl < 4; ++dtl)
#pragma unroll
        for (int r = 0; r < 4; ++r) {
            float v = acco[0][dtl][r] * linv[0] + acco[1][dtl][r] * linv[1]
                    + acco[2][dtl][r] * linv[2] + acco[3][dtl][r] * linv[3];
            v += __shfl_xor(v, 1); v += __shfl_xor(v, 2);
            v += __shfl_xor(v, 4); v += __shfl_xor(v, 8);
            if (l15 == 0) {
                int d = (wave * 4 + dtl) * 16 + quad * 4 + r;
                atomicAdd(&outp[b * 256 + d], v * (1.0f / 2048.0f));
            }
        }
}

extern "C" void kernel_launch(void* const* d_in, const int* in_sizes, int n_in,
                              void* d_out, int out_size, void* d_ws, size_t ws_size,
                              hipStream_t stream)
{
    const float* nodes = (const float*)d_in[0];
    const int*   mask  = (const int*)d_in[1];
    const float* Wq    = (const float*)d_in[2];
    const float* bq    = (const float*)d_in[3];
    const float* Wk    = (const float*)d_in[4];
    const float* bk    = (const float*)d_in[5];
    const float* Wv    = (const float*)d_in[6];
    const float* bv    = (const float*)d_in[7];
    float* out = (float*)d_out;

    // workspace layout (ushort units)
    unsigned short* qb  = (unsigned short*)d_ws;        // 8 MB
    unsigned short* vbt = qb + 4194304;                 // 8 MB (V^T swz tiles)
    int*   cnt  = (int*)(vbt + 4194304);                // 64 B
    int*   slot_of = cnt + 16;                          // 64 KB
    unsigned short* kbt = (unsigned short*)(slot_of + 16384);  // 8 MB
    unsigned short* nbf = kbt + 4194304;                // 8 MB
    unsigned short* wbf = nbf + 4194304;                // 0.4 MB

    k_cc<<<2154, 256, 0, stream>>>(nodes, Wq, Wk, Wv, nbf, wbf,
                                   mask, cnt, slot_of, kbt, vbt, out);
    k_proj2b<<<dim3(128, 2, 3), 256, 0, stream>>>(nbf, wbf, bq, bk, bv,
                                                  slot_of, qb, kbt, vbt);
    k_attn<<<dim3(32, 8), 256, 0, stream>>>(qb, kbt, vbt, cnt, out);
}